// Round 1
// baseline (2794.471 us; speedup 1.0000x reference)
//
#include <hip/hip_runtime.h>
#include <hip/hip_bf16.h>
#include <math.h>

#define S_LEN 4096
#define DMODEL 768
#define NHEAD 12
#define HDIM 64
#define DFF_ 3072
#define MROWS 8192  // B*S

union F4 { float4 v; float f[4]; };

// ---------------- LayerNorm: one block per row (768 cols) ----------------
__global__ __launch_bounds__(256) void ln_kernel(const float* __restrict__ x,
                                                 const float* __restrict__ g,
                                                 const float* __restrict__ bta,
                                                 float* __restrict__ out) {
    const int row = blockIdx.x;
    const int t = threadIdx.x;
    const float* xr = x + (size_t)row * DMODEL;
    float v0 = xr[t], v1 = xr[t + 256], v2 = xr[t + 512];
    float s = v0 + v1 + v2;
    float ss = v0 * v0 + v1 * v1 + v2 * v2;
    for (int o = 32; o > 0; o >>= 1) {
        s += __shfl_down(s, o, 64);
        ss += __shfl_down(ss, o, 64);
    }
    __shared__ float sm[4], sm2[4];
    const int w = t >> 6, lane = t & 63;
    if (lane == 0) { sm[w] = s; sm2[w] = ss; }
    __syncthreads();
    s = sm[0] + sm[1] + sm[2] + sm[3];
    ss = sm2[0] + sm2[1] + sm2[2] + sm2[3];
    const float mu = s * (1.0f / DMODEL);
    const float var = ss * (1.0f / DMODEL) - mu * mu;
    const float rs = rsqrtf(var + 1e-5f);
    float* orow = out + (size_t)row * DMODEL;
    orow[t]       = (v0 - mu) * rs * g[t]       + bta[t];
    orow[t + 256] = (v1 - mu) * rs * g[t + 256] + bta[t + 256];
    orow[t + 512] = (v2 - mu) * rs * g[t + 512] + bta[t + 512];
}

// ---------------- Generic fp32 GEMM: C = [relu]( A@W + bias [+ R] ) ----------------
// 128x128 tile, BK=16, 256 threads, 8x8 micro-tile per thread.
// blockIdx.z selects among three (W,bias,C) triples (for fused QKV).
template<bool RELU, bool RES>
__global__ __launch_bounds__(256) void gemm_kernel(
    const float* __restrict__ A,
    const float* __restrict__ W0, const float* __restrict__ bias0, float* __restrict__ C0,
    const float* __restrict__ W1, const float* __restrict__ bias1, float* __restrict__ C1,
    const float* __restrict__ W2, const float* __restrict__ bias2, float* __restrict__ C2,
    const float* __restrict__ R, int M, int N, int K) {
    const float* W = W0; const float* bias = bias0; float* C = C0;
    if (blockIdx.z == 1) { W = W1; bias = bias1; C = C1; }
    if (blockIdx.z == 2) { W = W2; bias = bias2; C = C2; }

    __shared__ float As[16][132];  // stored transposed: As[k][m]
    __shared__ float Bs[16][132];  // Bs[k][n]

    const int tid = threadIdx.x;
    const int tx = tid & 15, ty = tid >> 4;
    const int row0 = blockIdx.y * 128, col0 = blockIdx.x * 128;
    const int arow = tid >> 1, acol = (tid & 1) << 3;        // A tile: 128 rows x 16 k
    const int bkr = tid >> 4, bcol = (tid & 15) << 3;        // B tile: 16 k x 128 n

    float acc[8][8] = {};
    const float* Ap = A + (size_t)(row0 + arow) * K + acol;
    const float* Wp = W + (size_t)bkr * N + col0 + bcol;

    for (int k0 = 0; k0 < K; k0 += 16) {
        F4 a0, a1;
        a0.v = *(const float4*)(Ap + k0);
        a1.v = *(const float4*)(Ap + k0 + 4);
        float4 b0 = *(const float4*)(Wp + (size_t)k0 * N);
        float4 b1 = *(const float4*)(Wp + (size_t)k0 * N + 4);
#pragma unroll
        for (int i = 0; i < 4; ++i) {
            As[acol + i][arow] = a0.f[i];
            As[acol + 4 + i][arow] = a1.f[i];
        }
        *(float4*)&Bs[bkr][bcol] = b0;
        *(float4*)&Bs[bkr][bcol + 4] = b1;
        __syncthreads();
#pragma unroll
        for (int k = 0; k < 16; ++k) {
            F4 av0, av1, bv0, bv1;
            av0.v = *(const float4*)&As[k][ty * 8];
            av1.v = *(const float4*)&As[k][ty * 8 + 4];
            bv0.v = *(const float4*)&Bs[k][tx * 8];
            bv1.v = *(const float4*)&Bs[k][tx * 8 + 4];
            float a[8], b[8];
#pragma unroll
            for (int i = 0; i < 4; ++i) { a[i] = av0.f[i]; a[i + 4] = av1.f[i]; b[i] = bv0.f[i]; b[i + 4] = bv1.f[i]; }
#pragma unroll
            for (int i = 0; i < 8; ++i)
#pragma unroll
                for (int j = 0; j < 8; ++j) acc[i][j] += a[i] * b[j];
        }
        __syncthreads();
    }

    const int crow = row0 + ty * 8, ccol = col0 + tx * 8;
#pragma unroll
    for (int i = 0; i < 8; ++i) {
        size_t base = (size_t)(crow + i) * N + ccol;
#pragma unroll
        for (int j0 = 0; j0 < 8; j0 += 4) {
            F4 r;
#pragma unroll
            for (int j = 0; j < 4; ++j) r.f[j] = acc[i][j0 + j] + bias[ccol + j0 + j];
            if (RES) {
                F4 rr; rr.v = *(const float4*)&R[base + j0];
#pragma unroll
                for (int j = 0; j < 4; ++j) r.f[j] += rr.f[j];
            }
            if (RELU) {
#pragma unroll
                for (int j = 0; j < 4; ++j) r.f[j] = fmaxf(r.f[j], 0.0f);
            }
            *(float4*)&C[base + j0] = r.v;
        }
    }
}

// ---------------- Fused causal attention (flash-style, fp32) ----------------
// grid: (S/64, H, B), block 256. Each block: 64 queries of one head.
__global__ __launch_bounds__(256) void attn_kernel(
    const float* __restrict__ Q, const float* __restrict__ K,
    const float* __restrict__ V, const int* __restrict__ amask,
    float* __restrict__ O) {
    const int qt = blockIdx.x, h = blockIdx.y, b = blockIdx.z;
    __shared__ float QsT[64][68];  // [d][q]
    __shared__ float KsT[64][68];  // [d][k]
    __shared__ float Vs[64][68];   // [k][d]
    __shared__ float Ps[64][68];   // [q][k]
    __shared__ float red[64][16];
    __shared__ float mrow[64], lrow[64], arow[64], mkadd[64];

    const int tid = threadIdx.x;
    const int tx = tid & 15, ty = tid >> 4;
    const int lr = tid >> 2, ld0 = (tid & 3) << 4;
    const float NEG_INF = -__builtin_huge_valf();

    {   // load Q tile, transposed into QsT[d][q]
        const float* qp = Q + (size_t)(b * S_LEN + qt * 64 + lr) * DMODEL + h * HDIM + ld0;
        F4 t0, t1, t2, t3;
        t0.v = *(const float4*)qp;       t1.v = *(const float4*)(qp + 4);
        t2.v = *(const float4*)(qp + 8); t3.v = *(const float4*)(qp + 12);
#pragma unroll
        for (int i = 0; i < 4; ++i) {
            QsT[ld0 + i][lr] = t0.f[i];  QsT[ld0 + 4 + i][lr] = t1.f[i];
            QsT[ld0 + 8 + i][lr] = t2.f[i]; QsT[ld0 + 12 + i][lr] = t3.f[i];
        }
    }
    if (tid < 64) { mrow[tid] = NEG_INF; lrow[tid] = 0.0f; }
    float acc[4][4] = {};
    const int sq0 = qt * 64 + ty * 4;

    for (int kt = 0; kt <= qt; ++kt) {
        __syncthreads();
        {   // load K (transposed) and V tiles
            const float* kp = K + (size_t)(b * S_LEN + kt * 64 + lr) * DMODEL + h * HDIM + ld0;
            F4 t0, t1, t2, t3;
            t0.v = *(const float4*)kp;       t1.v = *(const float4*)(kp + 4);
            t2.v = *(const float4*)(kp + 8); t3.v = *(const float4*)(kp + 12);
#pragma unroll
            for (int i = 0; i < 4; ++i) {
                KsT[ld0 + i][lr] = t0.f[i];  KsT[ld0 + 4 + i][lr] = t1.f[i];
                KsT[ld0 + 8 + i][lr] = t2.f[i]; KsT[ld0 + 12 + i][lr] = t3.f[i];
            }
            const float* vp = V + (size_t)(b * S_LEN + kt * 64 + lr) * DMODEL + h * HDIM + ld0;
            *(float4*)&Vs[lr][ld0]      = *(const float4*)vp;
            *(float4*)&Vs[lr][ld0 + 4]  = *(const float4*)(vp + 4);
            *(float4*)&Vs[lr][ld0 + 8]  = *(const float4*)(vp + 8);
            *(float4*)&Vs[lr][ld0 + 12] = *(const float4*)(vp + 12);
            if (tid < 64)
                mkadd[tid] = amask[b * S_LEN + kt * 64 + tid] ? 0.0f : NEG_INF;
        }
        __syncthreads();

        // S = Q K^T (per-thread 4x4)
        float sreg[4][4] = {};
#pragma unroll 4
        for (int d = 0; d < 64; ++d) {
            F4 qv, kv;
            qv.v = *(const float4*)&QsT[d][ty * 4];
            kv.v = *(const float4*)&KsT[d][tx * 4];
#pragma unroll
            for (int i = 0; i < 4; ++i)
#pragma unroll
                for (int j = 0; j < 4; ++j) sreg[i][j] += qv.f[i] * kv.f[j];
        }
        // scale + mask + local row max
        const int sk0 = kt * 64 + tx * 4;
        float rm[4];
#pragma unroll
        for (int i = 0; i < 4; ++i) {
            rm[i] = NEG_INF;
#pragma unroll
            for (int j = 0; j < 4; ++j) {
                float val = sreg[i][j] * 0.125f + mkadd[tx * 4 + j];
                if (sk0 + j > sq0 + i) val = NEG_INF;
                sreg[i][j] = val;
                rm[i] = fmaxf(rm[i], val);
            }
            red[ty * 4 + i][tx] = rm[i];
        }
        __syncthreads();
        if (tid < 64) {
            float m = mrow[tid];
            float ml = red[tid][0];
#pragma unroll
            for (int jj = 1; jj < 16; ++jj) ml = fmaxf(ml, red[tid][jj]);
            float mn = fmaxf(m, ml);
            mrow[tid] = mn;
            arow[tid] = __expf(m - mn);
        }
        __syncthreads();
        // exp + P store + local row sums
#pragma unroll
        for (int i = 0; i < 4; ++i) {
            const float mi = mrow[ty * 4 + i];
            F4 p; float srow = 0.0f;
#pragma unroll
            for (int j = 0; j < 4; ++j) {
                float e = __expf(sreg[i][j] - mi);
                p.f[j] = e; srow += e;
            }
            *(float4*)&Ps[ty * 4 + i][tx * 4] = p.v;
            red[ty * 4 + i][tx] = srow;
        }
        __syncthreads();
        if (tid < 64) {
            float ls = 0.0f;
#pragma unroll
            for (int jj = 0; jj < 16; ++jj) ls += red[tid][jj];
            lrow[tid] = lrow[tid] * arow[tid] + ls;
        }
        // O = O*alpha + P V
#pragma unroll
        for (int i = 0; i < 4; ++i) {
            const float ai = arow[ty * 4 + i];
#pragma unroll
            for (int j = 0; j < 4; ++j) acc[i][j] *= ai;
        }
#pragma unroll 2
        for (int k0 = 0; k0 < 64; k0 += 4) {
            F4 pv[4];
#pragma unroll
            for (int i = 0; i < 4; ++i) pv[i].v = *(const float4*)&Ps[ty * 4 + i][k0];
#pragma unroll
            for (int kk = 0; kk < 4; ++kk) {
                F4 vv; vv.v = *(const float4*)&Vs[k0 + kk][tx * 4];
#pragma unroll
                for (int i = 0; i < 4; ++i)
#pragma unroll
                    for (int j = 0; j < 4; ++j) acc[i][j] += pv[i].f[kk] * vv.f[j];
            }
        }
    }
    __syncthreads();
    const int c0 = h * HDIM + tx * 4;
#pragma unroll
    for (int i = 0; i < 4; ++i) {
        const float inv = 1.0f / lrow[ty * 4 + i];
        F4 o;
#pragma unroll
        for (int j = 0; j < 4; ++j) o.f[j] = acc[i][j] * inv;
        *(float4*)&O[(size_t)(b * S_LEN + sq0 + i) * DMODEL + c0] = o.v;
    }
}

// ---------------- launcher ----------------
extern "C" void kernel_launch(void* const* d_in, const int* in_sizes, int n_in,
                              void* d_out, int out_size, void* d_ws, size_t ws_size,
                              hipStream_t stream) {
    const float* x     = (const float*)d_in[0];
    const int*   amask = (const int*)  d_in[1];
    const float* ln1_g = (const float*)d_in[2];
    const float* ln1_b = (const float*)d_in[3];
    const float* ln2_g = (const float*)d_in[4];
    const float* ln2_b = (const float*)d_in[5];
    const float* Wq = (const float*)d_in[6];  const float* bq = (const float*)d_in[7];
    const float* Wk = (const float*)d_in[8];  const float* bk = (const float*)d_in[9];
    const float* Wv = (const float*)d_in[10]; const float* bv = (const float*)d_in[11];
    const float* Wo = (const float*)d_in[12]; const float* bo = (const float*)d_in[13];
    const float* W1 = (const float*)d_in[14]; const float* b1 = (const float*)d_in[15];
    const float* W2 = (const float*)d_in[16]; const float* b2 = (const float*)d_in[17];
    float* out = (float*)d_out;

    const size_t SZ = (size_t)MROWS * DMODEL;  // 6291456 elems
    float* ws   = (float*)d_ws;
    float* h    = ws;            // [0, SZ)
    float* q    = ws + SZ;       // [SZ, 2SZ)
    float* kbuf = ws + 2 * SZ;   // [2SZ, 3SZ)
    float* vbuf = ws + 3 * SZ;   // [3SZ, 4SZ)
    float* ctx  = ws + 4 * SZ;   // [4SZ, 5SZ)
    float* x1   = q;             // reuse q slot after attention
    float* h2   = h;             // reuse h slot after QKV
    float* f    = ws + 2 * SZ;   // [2SZ, 6SZ) spans kbuf/vbuf/ctx slots (free by then)

    // 1. LN1
    ln_kernel<<<MROWS, 256, 0, stream>>>(x, ln1_g, ln1_b, h);
    // 2. QKV (fused via blockIdx.z)
    gemm_kernel<false, false><<<dim3(DMODEL / 128, MROWS / 128, 3), 256, 0, stream>>>(
        h, Wq, bq, q, Wk, bk, kbuf, Wv, bv, vbuf, nullptr, MROWS, DMODEL, DMODEL);
    // 3. attention
    attn_kernel<<<dim3(S_LEN / 64, NHEAD, 2), 256, 0, stream>>>(q, kbuf, vbuf, amask, ctx);
    // 4. out proj + residual
    gemm_kernel<false, true><<<dim3(DMODEL / 128, MROWS / 128, 1), 256, 0, stream>>>(
        ctx, Wo, bo, x1, Wo, bo, x1, Wo, bo, x1, x, MROWS, DMODEL, DMODEL);
    // 5. LN2
    ln_kernel<<<MROWS, 256, 0, stream>>>(x1, ln2_g, ln2_b, h2);
    // 6. FF1 + relu
    gemm_kernel<true, false><<<dim3(DFF_ / 128, MROWS / 128, 1), 256, 0, stream>>>(
        h2, W1, b1, f, W1, b1, f, W1, b1, f, nullptr, MROWS, DFF_, DMODEL);
    // 7. FF2 + residual -> out
    gemm_kernel<false, true><<<dim3(DMODEL / 128, MROWS / 128, 1), 256, 0, stream>>>(
        f, W2, b2, out, W2, b2, out, W2, b2, out, x1, MROWS, DMODEL, DFF_);
}

// Round 2
// 1587.540 us; speedup vs baseline: 1.7603x; 1.7603x over previous
//
#include <hip/hip_runtime.h>
#include <hip/hip_bf16.h>
#include <math.h>

#define S_LEN 4096
#define DMODEL 768
#define NHEAD 12
#define HDIM 64
#define DFF_ 3072
#define MROWS 8192  // B*S

typedef __bf16 bf16;
typedef __bf16 bf16x4 __attribute__((ext_vector_type(4)));
typedef __bf16 bf16x8 __attribute__((ext_vector_type(8)));
typedef float f32x4 __attribute__((ext_vector_type(4)));

union F4 { float4 v; float f[4]; };

__device__ __forceinline__ void gld_lds16(void* lds, const void* g) {
    __builtin_amdgcn_global_load_lds(
        (const __attribute__((address_space(1))) unsigned int*)g,
        (__attribute__((address_space(3))) unsigned int*)lds, 16, 0, 0);
}

// ---------------- LayerNorm: one block per row (768 cols), templated output ----------------
template<typename OUT>
__global__ __launch_bounds__(256) void ln_kernel(const float* __restrict__ x,
                                                 const float* __restrict__ g,
                                                 const float* __restrict__ bta,
                                                 OUT* __restrict__ out) {
    const int row = blockIdx.x;
    const int t = threadIdx.x;
    const float* xr = x + (size_t)row * DMODEL;
    float v0 = xr[t], v1 = xr[t + 256], v2 = xr[t + 512];
    float s = v0 + v1 + v2;
    float ss = v0 * v0 + v1 * v1 + v2 * v2;
    for (int o = 32; o > 0; o >>= 1) {
        s += __shfl_down(s, o, 64);
        ss += __shfl_down(ss, o, 64);
    }
    __shared__ float sm[4], sm2[4];
    const int w = t >> 6, lane = t & 63;
    if (lane == 0) { sm[w] = s; sm2[w] = ss; }
    __syncthreads();
    s = sm[0] + sm[1] + sm[2] + sm[3];
    ss = sm2[0] + sm2[1] + sm2[2] + sm2[3];
    const float mu = s * (1.0f / DMODEL);
    const float var = ss * (1.0f / DMODEL) - mu * mu;
    const float rs = rsqrtf(var + 1e-5f);
    OUT* orow = out + (size_t)row * DMODEL;
    orow[t]       = (OUT)((v0 - mu) * rs * g[t]       + bta[t]);
    orow[t + 256] = (OUT)((v1 - mu) * rs * g[t + 256] + bta[t + 256]);
    orow[t + 512] = (OUT)((v2 - mu) * rs * g[t + 512] + bta[t + 512]);
}

// ---------------- weight transpose+convert: W fp32 [K][N] -> Wt bf16 [N][K] ----------------
__global__ __launch_bounds__(256) void wtrans_kernel(const float* __restrict__ W,
                                                     bf16* __restrict__ Wt,
                                                     int K, int N) {
    __shared__ float tile[64][65];
    const int tid = threadIdx.x;
    const int n0 = blockIdx.x * 64, k0 = blockIdx.y * 64;
    const int lr = tid >> 4, lc = (tid & 15) << 2;
#pragma unroll
    for (int i = 0; i < 4; ++i) {
        const int r = lr + i * 16;
        F4 w; w.v = *(const float4*)&W[(size_t)(k0 + r) * N + n0 + lc];
#pragma unroll
        for (int j = 0; j < 4; ++j) tile[r][lc + j] = w.f[j];
    }
    __syncthreads();
#pragma unroll
    for (int i = 0; i < 4; ++i) {
        const int n = lr + i * 16;
        bf16x4 o;
#pragma unroll
        for (int j = 0; j < 4; ++j) o[j] = (bf16)tile[lc + j][n];
        *(bf16x4*)&Wt[(size_t)(n0 + n) * K + k0 + lc] = o;
    }
}

// ---------------- bf16 MFMA GEMM (m97 structure) ----------------
// C = [relu]( A @ Wt^T + bias [+ R] ), A: bf16 [M][K], Wt: bf16 [N][K] (pre-transposed)
// 128x128 tile, BK=32, 256 threads (4 waves, each 64x64), 16x16x32 bf16 MFMA.
template<bool RELU, bool RES, bool OUT_BF16>
__global__ __launch_bounds__(256) void mgemm_kernel(
    const bf16* __restrict__ A,
    const bf16* __restrict__ Wt0, const float* __restrict__ bias0, void* __restrict__ C0,
    const bf16* __restrict__ Wt1, const float* __restrict__ bias1, void* __restrict__ C1,
    const bf16* __restrict__ Wt2, const float* __restrict__ bias2, void* __restrict__ C2,
    const float* __restrict__ R, int M, int N, int K) {
    const bf16* Wt = Wt0; const float* bias = bias0; void* C = C0;
    if (blockIdx.z == 1) { Wt = Wt1; bias = bias1; C = C1; }
    if (blockIdx.z == 2) { Wt = Wt2; bias = bias2; C = C2; }

    __shared__ bf16 As[128 * 32];  // row-major, 64 B per row
    __shared__ bf16 Bs[128 * 32];  // Wt rows (n-major), 64 B per row

    const int tid = threadIdx.x;
    const int wave = tid >> 6, lane = tid & 63;
    const int row0 = blockIdx.y * 128, col0 = blockIdx.x * 128;
    const int wr = (wave >> 1) * 64, wc = (wave & 1) * 64;
    const int mrow = lane & 15, kq = (lane >> 4) * 8;

    // staging coords: per wave, 2 issues of 16 rows (64 lanes x 16B = 1024 B)
    const int st_row = (lane >> 2);        // 0..15 within issue
    const int st_off = (lane & 3) * 16;    // byte offset within 64 B row

    f32x4 acc[4][4] = {};

    const char* Ab = (const char*)(A + (size_t)row0 * K);
    const char* Bb = (const char*)(Wt + (size_t)col0 * K);
    const size_t strideA = (size_t)K * 2;

    for (int k0 = 0; k0 < K; k0 += 32) {
#pragma unroll
        for (int issue = 0; issue < 2; ++issue) {
            const int r = wave * 32 + issue * 16 + st_row;
            gld_lds16((char*)As + (wave * 32 + issue * 16) * 64,
                      Ab + (size_t)r * strideA + k0 * 2 + st_off);
            gld_lds16((char*)Bs + (wave * 32 + issue * 16) * 64,
                      Bb + (size_t)r * strideA + k0 * 2 + st_off);
        }
        __syncthreads();
        bf16x8 af[4], bfr[4];
#pragma unroll
        for (int mi = 0; mi < 4; ++mi)
            af[mi] = *(const bf16x8*)&As[(wr + mi * 16 + mrow) * 32 + kq];
#pragma unroll
        for (int ni = 0; ni < 4; ++ni)
            bfr[ni] = *(const bf16x8*)&Bs[(wc + ni * 16 + mrow) * 32 + kq];
#pragma unroll
        for (int mi = 0; mi < 4; ++mi)
#pragma unroll
            for (int ni = 0; ni < 4; ++ni)
                acc[mi][ni] = __builtin_amdgcn_mfma_f32_16x16x32_bf16(
                    af[mi], bfr[ni], acc[mi][ni], 0, 0, 0);
        __syncthreads();
    }

    // epilogue: C/D layout col=lane&15, row=quad*4+reg
    const int quad = lane >> 4;
    float bv[4];
#pragma unroll
    for (int ni = 0; ni < 4; ++ni) bv[ni] = bias[col0 + wc + ni * 16 + mrow];
#pragma unroll
    for (int mi = 0; mi < 4; ++mi) {
#pragma unroll
        for (int r = 0; r < 4; ++r) {
            const int row = row0 + wr + mi * 16 + quad * 4 + r;
#pragma unroll
            for (int ni = 0; ni < 4; ++ni) {
                const int col = col0 + wc + ni * 16 + mrow;
                float v = acc[mi][ni][r] + bv[ni];
                if (RES) v += R[(size_t)row * N + col];
                if (RELU) v = fmaxf(v, 0.0f);
                if (OUT_BF16) ((bf16*)C)[(size_t)row * N + col] = (bf16)v;
                else          ((float*)C)[(size_t)row * N + col] = v;
            }
        }
    }
}

// ---------------- Fused causal attention (flash-style, fp32 in, bf16 out) ----------------
__global__ __launch_bounds__(256) void attn_kernel(
    const float* __restrict__ Q, const float* __restrict__ K,
    const float* __restrict__ V, const int* __restrict__ amask,
    bf16* __restrict__ O) {
    const int qt = blockIdx.x, h = blockIdx.y, b = blockIdx.z;
    __shared__ float QsT[64][68];
    __shared__ float KsT[64][68];
    __shared__ float Vs[64][68];
    __shared__ float Ps[64][68];
    __shared__ float red[64][16];
    __shared__ float mrow[64], lrow[64], arow[64], mkadd[64];

    const int tid = threadIdx.x;
    const int tx = tid & 15, ty = tid >> 4;
    const int lr = tid >> 2, ld0 = (tid & 3) << 4;
    const float NEG_INF = -__builtin_huge_valf();

    {
        const float* qp = Q + (size_t)(b * S_LEN + qt * 64 + lr) * DMODEL + h * HDIM + ld0;
        F4 t0, t1, t2, t3;
        t0.v = *(const float4*)qp;       t1.v = *(const float4*)(qp + 4);
        t2.v = *(const float4*)(qp + 8); t3.v = *(const float4*)(qp + 12);
#pragma unroll
        for (int i = 0; i < 4; ++i) {
            QsT[ld0 + i][lr] = t0.f[i];  QsT[ld0 + 4 + i][lr] = t1.f[i];
            QsT[ld0 + 8 + i][lr] = t2.f[i]; QsT[ld0 + 12 + i][lr] = t3.f[i];
        }
    }
    if (tid < 64) { mrow[tid] = NEG_INF; lrow[tid] = 0.0f; }
    float acc[4][4] = {};
    const int sq0 = qt * 64 + ty * 4;

    for (int kt = 0; kt <= qt; ++kt) {
        __syncthreads();
        {
            const float* kp = K + (size_t)(b * S_LEN + kt * 64 + lr) * DMODEL + h * HDIM + ld0;
            F4 t0, t1, t2, t3;
            t0.v = *(const float4*)kp;       t1.v = *(const float4*)(kp + 4);
            t2.v = *(const float4*)(kp + 8); t3.v = *(const float4*)(kp + 12);
#pragma unroll
            for (int i = 0; i < 4; ++i) {
                KsT[ld0 + i][lr] = t0.f[i];  KsT[ld0 + 4 + i][lr] = t1.f[i];
                KsT[ld0 + 8 + i][lr] = t2.f[i]; KsT[ld0 + 12 + i][lr] = t3.f[i];
            }
            const float* vp = V + (size_t)(b * S_LEN + kt * 64 + lr) * DMODEL + h * HDIM + ld0;
            *(float4*)&Vs[lr][ld0]      = *(const float4*)vp;
            *(float4*)&Vs[lr][ld0 + 4]  = *(const float4*)(vp + 4);
            *(float4*)&Vs[lr][ld0 + 8]  = *(const float4*)(vp + 8);
            *(float4*)&Vs[lr][ld0 + 12] = *(const float4*)(vp + 12);
            if (tid < 64)
                mkadd[tid] = amask[b * S_LEN + kt * 64 + tid] ? 0.0f : NEG_INF;
        }
        __syncthreads();

        float sreg[4][4] = {};
#pragma unroll 4
        for (int d = 0; d < 64; ++d) {
            F4 qv, kv;
            qv.v = *(const float4*)&QsT[d][ty * 4];
            kv.v = *(const float4*)&KsT[d][tx * 4];
#pragma unroll
            for (int i = 0; i < 4; ++i)
#pragma unroll
                for (int j = 0; j < 4; ++j) sreg[i][j] += qv.f[i] * kv.f[j];
        }
        const int sk0 = kt * 64 + tx * 4;
        float rm[4];
#pragma unroll
        for (int i = 0; i < 4; ++i) {
            rm[i] = NEG_INF;
#pragma unroll
            for (int j = 0; j < 4; ++j) {
                float val = sreg[i][j] * 0.125f + mkadd[tx * 4 + j];
                if (sk0 + j > sq0 + i) val = NEG_INF;
                sreg[i][j] = val;
                rm[i] = fmaxf(rm[i], val);
            }
            red[ty * 4 + i][tx] = rm[i];
        }
        __syncthreads();
        if (tid < 64) {
            float m = mrow[tid];
            float ml = red[tid][0];
#pragma unroll
            for (int jj = 1; jj < 16; ++jj) ml = fmaxf(ml, red[tid][jj]);
            float mn = fmaxf(m, ml);
            mrow[tid] = mn;
            arow[tid] = __expf(m - mn);
        }
        __syncthreads();
#pragma unroll
        for (int i = 0; i < 4; ++i) {
            const float mi = mrow[ty * 4 + i];
            F4 p; float srow = 0.0f;
#pragma unroll
            for (int j = 0; j < 4; ++j) {
                float e = __expf(sreg[i][j] - mi);
                p.f[j] = e; srow += e;
            }
            *(float4*)&Ps[ty * 4 + i][tx * 4] = p.v;
            red[ty * 4 + i][tx] = srow;
        }
        __syncthreads();
        if (tid < 64) {
            float ls = 0.0f;
#pragma unroll
            for (int jj = 0; jj < 16; ++jj) ls += red[tid][jj];
            lrow[tid] = lrow[tid] * arow[tid] + ls;
        }
#pragma unroll
        for (int i = 0; i < 4; ++i) {
            const float ai = arow[ty * 4 + i];
#pragma unroll
            for (int j = 0; j < 4; ++j) acc[i][j] *= ai;
        }
#pragma unroll 2
        for (int k0 = 0; k0 < 64; k0 += 4) {
            F4 pv[4];
#pragma unroll
            for (int i = 0; i < 4; ++i) pv[i].v = *(const float4*)&Ps[ty * 4 + i][k0];
#pragma unroll
            for (int kk = 0; kk < 4; ++kk) {
                F4 vv; vv.v = *(const float4*)&Vs[k0 + kk][tx * 4];
#pragma unroll
                for (int i = 0; i < 4; ++i)
#pragma unroll
                    for (int j = 0; j < 4; ++j) acc[i][j] += pv[i].f[kk] * vv.f[j];
            }
        }
    }
    __syncthreads();
    const int c0 = h * HDIM + tx * 4;
#pragma unroll
    for (int i = 0; i < 4; ++i) {
        const float inv = 1.0f / lrow[ty * 4 + i];
        bf16x4 o;
#pragma unroll
        for (int j = 0; j < 4; ++j) o[j] = (bf16)(acc[i][j] * inv);
        *(bf16x4*)&O[(size_t)(b * S_LEN + sq0 + i) * DMODEL + c0] = o;
    }
}

// ---------------- launcher ----------------
extern "C" void kernel_launch(void* const* d_in, const int* in_sizes, int n_in,
                              void* d_out, int out_size, void* d_ws, size_t ws_size,
                              hipStream_t stream) {
    const float* x     = (const float*)d_in[0];
    const int*   amask = (const int*)  d_in[1];
    const float* ln1_g = (const float*)d_in[2];
    const float* ln1_b = (const float*)d_in[3];
    const float* ln2_g = (const float*)d_in[4];
    const float* ln2_b = (const float*)d_in[5];
    const float* Wq = (const float*)d_in[6];  const float* bq = (const float*)d_in[7];
    const float* Wk = (const float*)d_in[8];  const float* bk = (const float*)d_in[9];
    const float* Wv = (const float*)d_in[10]; const float* bv = (const float*)d_in[11];
    const float* Wo = (const float*)d_in[12]; const float* bo = (const float*)d_in[13];
    const float* W1 = (const float*)d_in[14]; const float* b1 = (const float*)d_in[15];
    const float* W2 = (const float*)d_in[16]; const float* b2 = (const float*)d_in[17];
    float* out = (float*)d_out;

    char* ws = (char*)d_ws;
    const size_t WSML = (size_t)DMODEL * DMODEL * 2;       // 1179648 B
    const size_t WBIG = (size_t)DMODEL * DFF_ * 2;         // 4718592 B
    bf16* Wqt = (bf16*)(ws + 0 * WSML);
    bf16* Wkt = (bf16*)(ws + 1 * WSML);
    bf16* Wvt = (bf16*)(ws + 2 * WSML);
    bf16* Wot = (bf16*)(ws + 3 * WSML);
    bf16* W1t = (bf16*)(ws + 4 * WSML);
    bf16* W2t = (bf16*)(ws + 4 * WSML + WBIG);
    char* act = ws + 4 * WSML + 2 * WBIG;                  // 14155776

    const size_t HB = (size_t)MROWS * DMODEL * 2;          // 12582912 (bf16 act)
    const size_t FB = (size_t)MROWS * DMODEL * 4;          // 25165824 (fp32 act)
    bf16*  h    = (bf16*)(act);                 // LN1 out (bf16); later h2
    float* q    = (float*)(act + HB);           // q fp32; later x1 fp32
    float* kbuf = (float*)(act + HB + FB);      // k fp32
    float* vbuf = (float*)(act + HB + 2 * FB);  // v fp32; later f (part 1)
    bf16*  ctxb = (bf16*)(act + HB + 3 * FB);   // attn out bf16; later f (part 2)
    float* x1   = q;
    bf16*  h2   = h;
    bf16*  f    = (bf16*)(act + HB + 2 * FB);   // FF1 out bf16, spans v+ctx regions

    // 0. weight transpose+convert (fp32 [K][N] -> bf16 [N][K])
    wtrans_kernel<<<dim3(DMODEL / 64, DMODEL / 64), 256, 0, stream>>>(Wq, Wqt, DMODEL, DMODEL);
    wtrans_kernel<<<dim3(DMODEL / 64, DMODEL / 64), 256, 0, stream>>>(Wk, Wkt, DMODEL, DMODEL);
    wtrans_kernel<<<dim3(DMODEL / 64, DMODEL / 64), 256, 0, stream>>>(Wv, Wvt, DMODEL, DMODEL);
    wtrans_kernel<<<dim3(DMODEL / 64, DMODEL / 64), 256, 0, stream>>>(Wo, Wot, DMODEL, DMODEL);
    wtrans_kernel<<<dim3(DFF_ / 64, DMODEL / 64), 256, 0, stream>>>(W1, W1t, DMODEL, DFF_);
    wtrans_kernel<<<dim3(DMODEL / 64, DFF_ / 64), 256, 0, stream>>>(W2, W2t, DFF_, DMODEL);

    // 1. LN1 -> h (bf16)
    ln_kernel<bf16><<<MROWS, 256, 0, stream>>>(x, ln1_g, ln1_b, h);
    // 2. QKV (fused via blockIdx.z), fp32 out
    mgemm_kernel<false, false, false><<<dim3(DMODEL / 128, MROWS / 128, 3), 256, 0, stream>>>(
        h, Wqt, bq, q, Wkt, bk, kbuf, Wvt, bv, vbuf, nullptr, MROWS, DMODEL, DMODEL);
    // 3. attention (fp32 compute, bf16 out)
    attn_kernel<<<dim3(S_LEN / 64, NHEAD, 2), 256, 0, stream>>>(q, kbuf, vbuf, amask, ctxb);
    // 4. out proj + residual(x) -> x1 fp32
    mgemm_kernel<false, true, false><<<dim3(DMODEL / 128, MROWS / 128, 1), 256, 0, stream>>>(
        ctxb, Wot, bo, x1, Wot, bo, x1, Wot, bo, x1, x, MROWS, DMODEL, DMODEL);
    // 5. LN2 -> h2 (bf16)
    ln_kernel<bf16><<<MROWS, 256, 0, stream>>>(x1, ln2_g, ln2_b, h2);
    // 6. FF1 + relu -> f (bf16)
    mgemm_kernel<true, false, true><<<dim3(DFF_ / 128, MROWS / 128, 1), 256, 0, stream>>>(
        h2, W1t, b1, f, W1t, b1, f, W1t, b1, f, nullptr, MROWS, DFF_, DMODEL);
    // 7. FF2 + residual(x1) -> out fp32
    mgemm_kernel<false, true, false><<<dim3(DMODEL / 128, MROWS / 128, 1), 256, 0, stream>>>(
        f, W2t, b2, out, W2t, b2, out, W2t, b2, out, x1, MROWS, DMODEL, DFF_);
}

// Round 3
// 738.129 us; speedup vs baseline: 3.7859x; 2.1508x over previous
//
#include <hip/hip_runtime.h>
#include <hip/hip_bf16.h>
#include <math.h>

#define S_LEN 4096
#define DMODEL 768
#define NHEAD 12
#define HDIM 64
#define DFF_ 3072
#define MROWS 8192  // B*S

typedef __bf16 bf16;
typedef __bf16 bf16x4 __attribute__((ext_vector_type(4)));
typedef __bf16 bf16x8 __attribute__((ext_vector_type(8)));
typedef float f32x4 __attribute__((ext_vector_type(4)));

union F4 { float4 v; float f[4]; };

__device__ __forceinline__ void gld_lds16(void* lds, const void* g) {
    __builtin_amdgcn_global_load_lds(
        (const __attribute__((address_space(1))) unsigned int*)g,
        (__attribute__((address_space(3))) unsigned int*)lds, 16, 0, 0);
}

// ---------------- LayerNorm ----------------
template<typename OUT>
__global__ __launch_bounds__(256) void ln_kernel(const float* __restrict__ x,
                                                 const float* __restrict__ g,
                                                 const float* __restrict__ bta,
                                                 OUT* __restrict__ out) {
    const int row = blockIdx.x;
    const int t = threadIdx.x;
    const float* xr = x + (size_t)row * DMODEL;
    float v0 = xr[t], v1 = xr[t + 256], v2 = xr[t + 512];
    float s = v0 + v1 + v2;
    float ss = v0 * v0 + v1 * v1 + v2 * v2;
    for (int o = 32; o > 0; o >>= 1) {
        s += __shfl_down(s, o, 64);
        ss += __shfl_down(ss, o, 64);
    }
    __shared__ float sm[4], sm2[4];
    const int w = t >> 6, lane = t & 63;
    if (lane == 0) { sm[w] = s; sm2[w] = ss; }
    __syncthreads();
    s = sm[0] + sm[1] + sm[2] + sm[3];
    ss = sm2[0] + sm2[1] + sm2[2] + sm2[3];
    const float mu = s * (1.0f / DMODEL);
    const float var = ss * (1.0f / DMODEL) - mu * mu;
    const float rs = rsqrtf(var + 1e-5f);
    OUT* orow = out + (size_t)row * DMODEL;
    orow[t]       = (OUT)((v0 - mu) * rs * g[t]       + bta[t]);
    orow[t + 256] = (OUT)((v1 - mu) * rs * g[t + 256] + bta[t + 256]);
    orow[t + 512] = (OUT)((v2 - mu) * rs * g[t + 512] + bta[t + 512]);
}

// ---------------- weight transpose+convert: fp32 [K][N] -> bf16 [N][K] ----------------
__global__ __launch_bounds__(256) void wtrans_kernel(const float* __restrict__ W,
                                                     bf16* __restrict__ Wt,
                                                     int K, int N) {
    __shared__ float tile[64][65];
    const int tid = threadIdx.x;
    const int n0 = blockIdx.x * 64, k0 = blockIdx.y * 64;
    const int lr = tid >> 4, lc = (tid & 15) << 2;
#pragma unroll
    for (int i = 0; i < 4; ++i) {
        const int r = lr + i * 16;
        F4 w; w.v = *(const float4*)&W[(size_t)(k0 + r) * N + n0 + lc];
#pragma unroll
        for (int j = 0; j < 4; ++j) tile[r][lc + j] = w.f[j];
    }
    __syncthreads();
#pragma unroll
    for (int i = 0; i < 4; ++i) {
        const int n = lr + i * 16;
        bf16x4 o;
#pragma unroll
        for (int j = 0; j < 4; ++j) o[j] = (bf16)tile[lc + j][n];
        *(bf16x4*)&Wt[(size_t)(n0 + n) * K + k0 + lc] = o;
    }
}

// ---------------- bf16 MFMA GEMM (m97 structure) ----------------
template<bool RELU, bool RES, bool OUT_BF16>
__global__ __launch_bounds__(256) void mgemm_kernel(
    const bf16* __restrict__ A,
    const bf16* __restrict__ Wt0, const float* __restrict__ bias0, void* __restrict__ C0,
    const bf16* __restrict__ Wt1, const float* __restrict__ bias1, void* __restrict__ C1,
    const bf16* __restrict__ Wt2, const float* __restrict__ bias2, void* __restrict__ C2,
    const float* __restrict__ R, int M, int N, int K) {
    const bf16* Wt = Wt0; const float* bias = bias0; void* C = C0;
    if (blockIdx.z == 1) { Wt = Wt1; bias = bias1; C = C1; }
    if (blockIdx.z == 2) { Wt = Wt2; bias = bias2; C = C2; }

    __shared__ bf16 As[128 * 32];
    __shared__ bf16 Bs[128 * 32];

    const int tid = threadIdx.x;
    const int wave = tid >> 6, lane = tid & 63;
    const int row0 = blockIdx.y * 128, col0 = blockIdx.x * 128;
    const int wr = (wave >> 1) * 64, wc = (wave & 1) * 64;
    const int mrow = lane & 15, kq = (lane >> 4) * 8;

    const int st_row = (lane >> 2);
    const int st_off = (lane & 3) * 16;

    f32x4 acc[4][4] = {};

    const char* Ab = (const char*)(A + (size_t)row0 * K);
    const char* Bb = (const char*)(Wt + (size_t)col0 * K);
    const size_t strideA = (size_t)K * 2;

    for (int k0 = 0; k0 < K; k0 += 32) {
#pragma unroll
        for (int issue = 0; issue < 2; ++issue) {
            const int r = wave * 32 + issue * 16 + st_row;
            gld_lds16((char*)As + (wave * 32 + issue * 16) * 64,
                      Ab + (size_t)r * strideA + k0 * 2 + st_off);
            gld_lds16((char*)Bs + (wave * 32 + issue * 16) * 64,
                      Bb + (size_t)r * strideA + k0 * 2 + st_off);
        }
        __syncthreads();
        bf16x8 af[4], bfr[4];
#pragma unroll
        for (int mi = 0; mi < 4; ++mi)
            af[mi] = *(const bf16x8*)&As[(wr + mi * 16 + mrow) * 32 + kq];
#pragma unroll
        for (int ni = 0; ni < 4; ++ni)
            bfr[ni] = *(const bf16x8*)&Bs[(wc + ni * 16 + mrow) * 32 + kq];
#pragma unroll
        for (int mi = 0; mi < 4; ++mi)
#pragma unroll
            for (int ni = 0; ni < 4; ++ni)
                acc[mi][ni] = __builtin_amdgcn_mfma_f32_16x16x32_bf16(
                    af[mi], bfr[ni], acc[mi][ni], 0, 0, 0);
        __syncthreads();
    }

    const int quad = lane >> 4;
    float bv[4];
#pragma unroll
    for (int ni = 0; ni < 4; ++ni) bv[ni] = bias[col0 + wc + ni * 16 + mrow];
#pragma unroll
    for (int mi = 0; mi < 4; ++mi) {
#pragma unroll
        for (int r = 0; r < 4; ++r) {
            const int row = row0 + wr + mi * 16 + quad * 4 + r;
#pragma unroll
            for (int ni = 0; ni < 4; ++ni) {
                const int col = col0 + wc + ni * 16 + mrow;
                float v = acc[mi][ni][r] + bv[ni];
                if (RES) v += R[(size_t)row * N + col];
                if (RELU) v = fmaxf(v, 0.0f);
                if (OUT_BF16) ((bf16*)C)[(size_t)row * N + col] = (bf16)v;
                else          ((float*)C)[(size_t)row * N + col] = v;
            }
        }
    }
}

// ---------------- MFMA flash attention (bf16 in, bf16 out) ----------------
// grid: (S/64, H, B), 256 threads = 4 waves. Wave w owns queries 16w..16w+15
// of the block's 64-query tile. K-tile = 64 keys per iteration.
__global__ __launch_bounds__(256) void mattn_kernel(
    const bf16* __restrict__ Q, const bf16* __restrict__ K,
    const bf16* __restrict__ V, const int* __restrict__ amask,
    bf16* __restrict__ O) {
    const int qt = gridDim.x - 1 - blockIdx.x;  // heavy tiles first
    const int h = blockIdx.y, b = blockIdx.z;

    __shared__ bf16 Ks[64][68];  // [key][d]
    __shared__ bf16 Vt[64][68];  // [d][key]
    __shared__ bf16 Ps[64][68];  // [q][key]; reused for O epilogue
    __shared__ float mk[64];

    const int tid = threadIdx.x;
    const int wave = tid >> 6, lane = tid & 63;
    const int l = lane & 15, quad = lane >> 4;
    const float NEG_INF = -__builtin_huge_valf();
    const float SCL = 0.125f * 1.44269504089f;  // 1/sqrt(64) * log2(e)

    // Q fragments (A-layout), held in registers for the whole block
    const bf16* Qb = Q + (size_t)(b * S_LEN + qt * 64 + wave * 16 + l) * DMODEL + h * HDIM;
    bf16x8 qf[2];
    qf[0] = *(const bf16x8*)(Qb + quad * 8);
    qf[1] = *(const bf16x8*)(Qb + 32 + quad * 8);

    float m_run[4], l_run[4];
    f32x4 acc[4] = {};
#pragma unroll
    for (int r = 0; r < 4; ++r) { m_run[r] = NEG_INF; l_run[r] = 0.0f; }

    // staging coords
    const int krow = tid >> 2, kseg = (tid & 3) * 16;   // K: [key][d]
    const int vkey = lane, vd0 = wave * 16;             // V: transpose

    for (int kt = 0; kt <= qt; ++kt) {
        __syncthreads();  // prior iter's LDS reads complete
        {   // stage K tile [key][d]
            const bf16* Kg = K + (size_t)(b * S_LEN + kt * 64 + krow) * DMODEL + h * HDIM + kseg;
            bf16x8 k0 = *(const bf16x8*)Kg;
            bf16x8 k1 = *(const bf16x8*)(Kg + 8);
            *(bf16x8*)&Ks[krow][kseg] = k0;
            *(bf16x8*)&Ks[krow][kseg + 8] = k1;
        }
        {   // stage V tile transposed [d][key]
            const bf16* Vg = V + (size_t)(b * S_LEN + kt * 64 + vkey) * DMODEL + h * HDIM + vd0;
            bf16x8 v0 = *(const bf16x8*)Vg;
            bf16x8 v1 = *(const bf16x8*)(Vg + 8);
#pragma unroll
            for (int i = 0; i < 8; ++i) {
                Vt[vd0 + i][vkey] = v0[i];
                Vt[vd0 + 8 + i][vkey] = v1[i];
            }
        }
        if (tid < 64)
            mk[tid] = amask[b * S_LEN + kt * 64 + tid] ? 0.0f : NEG_INF;
        __syncthreads();

        // S = Q K^T : 4 tiles of 16q x 16k per wave
        f32x4 sreg[4] = {};
#pragma unroll
        for (int ni = 0; ni < 4; ++ni) {
            bf16x8 kf0 = *(const bf16x8*)&Ks[ni * 16 + l][quad * 8];
            bf16x8 kf1 = *(const bf16x8*)&Ks[ni * 16 + l][32 + quad * 8];
            sreg[ni] = __builtin_amdgcn_mfma_f32_16x16x32_bf16(qf[0], kf0, sreg[ni], 0, 0, 0);
            sreg[ni] = __builtin_amdgcn_mfma_f32_16x16x32_bf16(qf[1], kf1, sreg[ni], 0, 0, 0);
        }

        // scale + mask (log2 domain) + row max
        const bool diag = (kt == qt);
        float mloc[4] = {NEG_INF, NEG_INF, NEG_INF, NEG_INF};
#pragma unroll
        for (int ni = 0; ni < 4; ++ni) {
            const float madd = mk[ni * 16 + l];
            const int kk = ni * 16 + l;
#pragma unroll
            for (int r = 0; r < 4; ++r) {
                float s = sreg[ni][r] * SCL + madd;
                if (diag && kk > wave * 16 + quad * 4 + r) s = NEG_INF;
                sreg[ni][r] = s;
                mloc[r] = fmaxf(mloc[r], s);
            }
        }
#pragma unroll
        for (int r = 0; r < 4; ++r) {
            mloc[r] = fmaxf(mloc[r], __shfl_xor(mloc[r], 1, 16));
            mloc[r] = fmaxf(mloc[r], __shfl_xor(mloc[r], 2, 16));
            mloc[r] = fmaxf(mloc[r], __shfl_xor(mloc[r], 4, 16));
            mloc[r] = fmaxf(mloc[r], __shfl_xor(mloc[r], 8, 16));
        }
        float alpha[4], lsum[4];
#pragma unroll
        for (int r = 0; r < 4; ++r) {
            const float mn = fmaxf(m_run[r], mloc[r]);
            alpha[r] = exp2f(m_run[r] - mn);
            m_run[r] = mn;
            lsum[r] = 0.0f;
        }
        // P = exp2(s - m), accumulate row sums, write P to LDS (A-layout rows)
#pragma unroll
        for (int ni = 0; ni < 4; ++ni) {
#pragma unroll
            for (int r = 0; r < 4; ++r) {
                const float p = exp2f(sreg[ni][r] - m_run[r]);
                sreg[ni][r] = p;
                lsum[r] += p;
            }
        }
#pragma unroll
        for (int r = 0; r < 4; ++r) {
            lsum[r] += __shfl_xor(lsum[r], 1, 16);
            lsum[r] += __shfl_xor(lsum[r], 2, 16);
            lsum[r] += __shfl_xor(lsum[r], 4, 16);
            lsum[r] += __shfl_xor(lsum[r], 8, 16);
            l_run[r] = l_run[r] * alpha[r] + lsum[r];
        }
#pragma unroll
        for (int ni = 0; ni < 4; ++ni)
#pragma unroll
            for (int r = 0; r < 4; ++r)
                acc[ni][r] *= alpha[r];
#pragma unroll
        for (int ni = 0; ni < 4; ++ni)
#pragma unroll
            for (int r = 0; r < 4; ++r)
                Ps[wave * 16 + quad * 4 + r][ni * 16 + l] = (bf16)sreg[ni][r];
        __syncthreads();

        // O += P V  (A = P rows, B = Vt rows)
        bf16x8 pf0 = *(const bf16x8*)&Ps[wave * 16 + l][quad * 8];
        bf16x8 pf1 = *(const bf16x8*)&Ps[wave * 16 + l][32 + quad * 8];
#pragma unroll
        for (int ni = 0; ni < 4; ++ni) {
            bf16x8 vf0 = *(const bf16x8*)&Vt[ni * 16 + l][quad * 8];
            bf16x8 vf1 = *(const bf16x8*)&Vt[ni * 16 + l][32 + quad * 8];
            acc[ni] = __builtin_amdgcn_mfma_f32_16x16x32_bf16(pf0, vf0, acc[ni], 0, 0, 0);
            acc[ni] = __builtin_amdgcn_mfma_f32_16x16x32_bf16(pf1, vf1, acc[ni], 0, 0, 0);
        }
    }

    // epilogue: O = acc / l, LDS bounce for coalesced store
    __syncthreads();
    float rl[4];
#pragma unroll
    for (int r = 0; r < 4; ++r) rl[r] = 1.0f / l_run[r];
#pragma unroll
    for (int ni = 0; ni < 4; ++ni)
#pragma unroll
        for (int r = 0; r < 4; ++r)
            Ps[wave * 16 + quad * 4 + r][ni * 16 + l] = (bf16)(acc[ni][r] * rl[r]);
    __syncthreads();
    const int orow = tid >> 2, oseg = (tid & 3) * 16;
    bf16* Og = O + (size_t)(b * S_LEN + qt * 64 + orow) * DMODEL + h * HDIM + oseg;
    *(bf16x8*)Og = *(const bf16x8*)&Ps[orow][oseg];
    *(bf16x8*)(Og + 8) = *(const bf16x8*)&Ps[orow][oseg + 8];
}

// ---------------- launcher ----------------
extern "C" void kernel_launch(void* const* d_in, const int* in_sizes, int n_in,
                              void* d_out, int out_size, void* d_ws, size_t ws_size,
                              hipStream_t stream) {
    const float* x     = (const float*)d_in[0];
    const int*   amask = (const int*)  d_in[1];
    const float* ln1_g = (const float*)d_in[2];
    const float* ln1_b = (const float*)d_in[3];
    const float* ln2_g = (const float*)d_in[4];
    const float* ln2_b = (const float*)d_in[5];
    const float* Wq = (const float*)d_in[6];  const float* bq = (const float*)d_in[7];
    const float* Wk = (const float*)d_in[8];  const float* bk = (const float*)d_in[9];
    const float* Wv = (const float*)d_in[10]; const float* bv = (const float*)d_in[11];
    const float* Wo = (const float*)d_in[12]; const float* bo = (const float*)d_in[13];
    const float* W1 = (const float*)d_in[14]; const float* b1 = (const float*)d_in[15];
    const float* W2 = (const float*)d_in[16]; const float* b2 = (const float*)d_in[17];
    float* out = (float*)d_out;

    char* ws = (char*)d_ws;
    const size_t WSML = (size_t)DMODEL * DMODEL * 2;
    const size_t WBIG = (size_t)DMODEL * DFF_ * 2;
    bf16* Wqt = (bf16*)(ws + 0 * WSML);
    bf16* Wkt = (bf16*)(ws + 1 * WSML);
    bf16* Wvt = (bf16*)(ws + 2 * WSML);
    bf16* Wot = (bf16*)(ws + 3 * WSML);
    bf16* W1t = (bf16*)(ws + 4 * WSML);
    bf16* W2t = (bf16*)(ws + 4 * WSML + WBIG);
    char* act = ws + 4 * WSML + 2 * WBIG;

    const size_t HB = (size_t)MROWS * DMODEL * 2;   // bf16 activation
    const size_t FB = (size_t)MROWS * DMODEL * 4;   // fp32 activation
    bf16*  h    = (bf16*)(act);            // LN1 out; later ctx; later h2
    bf16*  qb   = (bf16*)(act + HB);
    bf16*  kb   = (bf16*)(act + 2 * HB);
    bf16*  vb   = (bf16*)(act + 3 * HB);
    bf16*  ctx  = h;                       // reuse (h dead after QKV)
    float* x1   = (float*)(act + 4 * HB);
    bf16*  f    = (bf16*)(act + 4 * HB + FB);
    bf16*  h2   = h;                       // reuse (ctx dead after Wo GEMM)

    // 0. weight transpose+convert
    wtrans_kernel<<<dim3(DMODEL / 64, DMODEL / 64), 256, 0, stream>>>(Wq, Wqt, DMODEL, DMODEL);
    wtrans_kernel<<<dim3(DMODEL / 64, DMODEL / 64), 256, 0, stream>>>(Wk, Wkt, DMODEL, DMODEL);
    wtrans_kernel<<<dim3(DMODEL / 64, DMODEL / 64), 256, 0, stream>>>(Wv, Wvt, DMODEL, DMODEL);
    wtrans_kernel<<<dim3(DMODEL / 64, DMODEL / 64), 256, 0, stream>>>(Wo, Wot, DMODEL, DMODEL);
    wtrans_kernel<<<dim3(DFF_ / 64, DMODEL / 64), 256, 0, stream>>>(W1, W1t, DMODEL, DFF_);
    wtrans_kernel<<<dim3(DMODEL / 64, DFF_ / 64), 256, 0, stream>>>(W2, W2t, DFF_, DMODEL);

    // 1. LN1 -> h (bf16)
    ln_kernel<bf16><<<MROWS, 256, 0, stream>>>(x, ln1_g, ln1_b, h);
    // 2. QKV fused, bf16 out
    mgemm_kernel<false, false, true><<<dim3(DMODEL / 128, MROWS / 128, 3), 256, 0, stream>>>(
        h, Wqt, bq, qb, Wkt, bk, kb, Wvt, bv, vb, nullptr, MROWS, DMODEL, DMODEL);
    // 3. MFMA flash attention -> ctx (bf16)
    mattn_kernel<<<dim3(S_LEN / 64, NHEAD, 2), 256, 0, stream>>>(qb, kb, vb, amask, ctx);
    // 4. out proj + residual(x) -> x1 (fp32)
    mgemm_kernel<false, true, false><<<dim3(DMODEL / 128, MROWS / 128, 1), 256, 0, stream>>>(
        ctx, Wot, bo, x1, Wot, bo, x1, Wot, bo, x1, x, MROWS, DMODEL, DMODEL);
    // 5. LN2 -> h2 (bf16)
    ln_kernel<bf16><<<MROWS, 256, 0, stream>>>(x1, ln2_g, ln2_b, h2);
    // 6. FF1 + relu -> f (bf16)
    mgemm_kernel<true, false, true><<<dim3(DFF_ / 128, MROWS / 128, 1), 256, 0, stream>>>(
        h2, W1t, b1, f, W1t, b1, f, W1t, b1, f, nullptr, MROWS, DFF_, DMODEL);
    // 7. FF2 + residual(x1) -> out (fp32)
    mgemm_kernel<false, true, false><<<dim3(DMODEL / 128, MROWS / 128, 1), 256, 0, stream>>>(
        f, W2t, b2, out, W2t, b2, out, W2t, b2, out, x1, MROWS, DMODEL, DFF_);
}

// Round 4
// 514.979 us; speedup vs baseline: 5.4264x; 1.4333x over previous
//
#include <hip/hip_runtime.h>
#include <hip/hip_bf16.h>
#include <math.h>

#define S_LEN 4096
#define DMODEL 768
#define NHEAD 12
#define HDIM 64
#define DFF_ 3072
#define MROWS 8192  // B*S

typedef __bf16 bf16;
typedef __bf16 bf16x4 __attribute__((ext_vector_type(4)));
typedef __bf16 bf16x8 __attribute__((ext_vector_type(8)));
typedef float f32x4 __attribute__((ext_vector_type(4)));

union F4 { float4 v; float f[4]; };
union U2 { bf16 h[2]; unsigned u; };
union U8 { unsigned u[4]; bf16x8 v; };

__device__ __forceinline__ void gld_lds16(void* lds, const void* g) {
    __builtin_amdgcn_global_load_lds(
        (const __attribute__((address_space(1))) unsigned int*)g,
        (__attribute__((address_space(3))) unsigned int*)lds, 16, 0, 0);
}

// ---------------- LayerNorm ----------------
template<typename OUT>
__global__ __launch_bounds__(256) void ln_kernel(const float* __restrict__ x,
                                                 const float* __restrict__ g,
                                                 const float* __restrict__ bta,
                                                 OUT* __restrict__ out) {
    const int row = blockIdx.x;
    const int t = threadIdx.x;
    const float* xr = x + (size_t)row * DMODEL;
    float v0 = xr[t], v1 = xr[t + 256], v2 = xr[t + 512];
    float s = v0 + v1 + v2;
    float ss = v0 * v0 + v1 * v1 + v2 * v2;
    for (int o = 32; o > 0; o >>= 1) {
        s += __shfl_down(s, o, 64);
        ss += __shfl_down(ss, o, 64);
    }
    __shared__ float sm[4], sm2[4];
    const int w = t >> 6, lane = t & 63;
    if (lane == 0) { sm[w] = s; sm2[w] = ss; }
    __syncthreads();
    s = sm[0] + sm[1] + sm[2] + sm[3];
    ss = sm2[0] + sm2[1] + sm2[2] + sm2[3];
    const float mu = s * (1.0f / DMODEL);
    const float var = ss * (1.0f / DMODEL) - mu * mu;
    const float rs = rsqrtf(var + 1e-5f);
    OUT* orow = out + (size_t)row * DMODEL;
    orow[t]       = (OUT)((v0 - mu) * rs * g[t]       + bta[t]);
    orow[t + 256] = (OUT)((v1 - mu) * rs * g[t + 256] + bta[t + 256]);
    orow[t + 512] = (OUT)((v2 - mu) * rs * g[t + 512] + bta[t + 512]);
}

// ---------------- weight transpose+convert: fp32 [K][N] -> bf16 [N][K] ----------------
__global__ __launch_bounds__(256) void wtrans_kernel(const float* __restrict__ W,
                                                     bf16* __restrict__ Wt,
                                                     int K, int N) {
    __shared__ float tile[64][65];
    const int tid = threadIdx.x;
    const int n0 = blockIdx.x * 64, k0 = blockIdx.y * 64;
    const int lr = tid >> 4, lc = (tid & 15) << 2;
#pragma unroll
    for (int i = 0; i < 4; ++i) {
        const int r = lr + i * 16;
        F4 w; w.v = *(const float4*)&W[(size_t)(k0 + r) * N + n0 + lc];
#pragma unroll
        for (int j = 0; j < 4; ++j) tile[r][lc + j] = w.f[j];
    }
    __syncthreads();
#pragma unroll
    for (int i = 0; i < 4; ++i) {
        const int n = lr + i * 16;
        bf16x4 o;
#pragma unroll
        for (int j = 0; j < 4; ++j) o[j] = (bf16)tile[lc + j][n];
        *(bf16x4*)&Wt[(size_t)(n0 + n) * K + k0 + lc] = o;
    }
}

// ---------------- bf16 MFMA GEMM (m97 structure) ----------------
template<bool RELU, bool RES, bool OUT_BF16>
__global__ __launch_bounds__(256) void mgemm_kernel(
    const bf16* __restrict__ A,
    const bf16* __restrict__ Wt0, const float* __restrict__ bias0, void* __restrict__ C0,
    const bf16* __restrict__ Wt1, const float* __restrict__ bias1, void* __restrict__ C1,
    const bf16* __restrict__ Wt2, const float* __restrict__ bias2, void* __restrict__ C2,
    const float* __restrict__ R, int M, int N, int K,
    float sc0, float sc1, float sc2) {
    const bf16* Wt = Wt0; const float* bias = bias0; void* C = C0; float sc = sc0;
    if (blockIdx.z == 1) { Wt = Wt1; bias = bias1; C = C1; sc = sc1; }
    if (blockIdx.z == 2) { Wt = Wt2; bias = bias2; C = C2; sc = sc2; }

    __shared__ bf16 As[128 * 32];
    __shared__ bf16 Bs[128 * 32];

    const int tid = threadIdx.x;
    const int wave = tid >> 6, lane = tid & 63;
    const int row0 = blockIdx.y * 128, col0 = blockIdx.x * 128;
    const int wr = (wave >> 1) * 64, wc = (wave & 1) * 64;
    const int mrow = lane & 15, kq = (lane >> 4) * 8;

    const int st_row = (lane >> 2);
    const int st_off = (lane & 3) * 16;

    f32x4 acc[4][4] = {};

    const char* Ab = (const char*)(A + (size_t)row0 * K);
    const char* Bb = (const char*)(Wt + (size_t)col0 * K);
    const size_t strideA = (size_t)K * 2;

    for (int k0 = 0; k0 < K; k0 += 32) {
#pragma unroll
        for (int issue = 0; issue < 2; ++issue) {
            const int r = wave * 32 + issue * 16 + st_row;
            gld_lds16((char*)As + (wave * 32 + issue * 16) * 64,
                      Ab + (size_t)r * strideA + k0 * 2 + st_off);
            gld_lds16((char*)Bs + (wave * 32 + issue * 16) * 64,
                      Bb + (size_t)r * strideA + k0 * 2 + st_off);
        }
        __syncthreads();
        bf16x8 af[4], bfr[4];
#pragma unroll
        for (int mi = 0; mi < 4; ++mi)
            af[mi] = *(const bf16x8*)&As[(wr + mi * 16 + mrow) * 32 + kq];
#pragma unroll
        for (int ni = 0; ni < 4; ++ni)
            bfr[ni] = *(const bf16x8*)&Bs[(wc + ni * 16 + mrow) * 32 + kq];
#pragma unroll
        for (int mi = 0; mi < 4; ++mi)
#pragma unroll
            for (int ni = 0; ni < 4; ++ni)
                acc[mi][ni] = __builtin_amdgcn_mfma_f32_16x16x32_bf16(
                    af[mi], bfr[ni], acc[mi][ni], 0, 0, 0);
        __syncthreads();
    }

    const int quad = lane >> 4;
    float bv[4];
#pragma unroll
    for (int ni = 0; ni < 4; ++ni) bv[ni] = bias[col0 + wc + ni * 16 + mrow];
#pragma unroll
    for (int mi = 0; mi < 4; ++mi) {
#pragma unroll
        for (int r = 0; r < 4; ++r) {
            const int row = row0 + wr + mi * 16 + quad * 4 + r;
#pragma unroll
            for (int ni = 0; ni < 4; ++ni) {
                const int col = col0 + wc + ni * 16 + mrow;
                float v = acc[mi][ni][r] + bv[ni];
                if (RES) v += R[(size_t)row * N + col];
                v *= sc;
                if (RELU) v = fmaxf(v, 0.0f);
                if (OUT_BF16) ((bf16*)C)[(size_t)row * N + col] = (bf16)v;
                else          ((float*)C)[(size_t)row * N + col] = v;
            }
        }
    }
}

// ---------------- Transposed-S MFMA flash attention ----------------
// Computes S^T = K·Q^T so each lane's C-column is a fixed query (q = lane&15).
// P^T re-layout for PV (O^T = V^T · P^T) done via quad-level shfl — no LDS
// round trip, no third barrier. Q pre-scaled by 0.125*log2(e) in QKV epilogue.
// grid: (32, H, B); block = 4 waves; each block does q-tiles {63-bx, bx}
// sequentially -> uniform 65 K-iterations per block (load balance).
__global__ __launch_bounds__(256) void mattn_kernel(
    const bf16* __restrict__ Q, const bf16* __restrict__ K,
    const bf16* __restrict__ V, const int* __restrict__ amask,
    bf16* __restrict__ O) {
    const int bx = blockIdx.x, h = blockIdx.y, b = blockIdx.z;

    __shared__ bf16 Ks[64][72];   // [key][d]   (144 B rows: 16B-aligned b128)
    __shared__ bf16 Vt[64][72];   // [d][key]
    __shared__ bf16 Os[64][72];   // epilogue bounce
    __shared__ float mk[64];
    __shared__ int flagv;

    const int tid = threadIdx.x;
    const int wave = tid >> 6, lane = tid & 63;
    const int l = lane & 15, quad = lane >> 4;
    const int qh = quad >> 1;                    // selects mi-group in P shfl
    const int srcA = (quad & 1) * 32 + l;        // P^T redistribution sources
    const int srcB = srcA + 16;
    const float NEG_INF = -__builtin_huge_valf();

    // staging coords
    const int kr = tid >> 2, ks = (tid & 3) * 16;          // K tile
    const int vk0 = (tid & 31) * 2, vds = (tid >> 5) * 8;  // V transpose

#pragma unroll 1
    for (int pass = 0; pass < 2; ++pass) {
        const int qt = pass ? bx : (63 - bx);

        // Q fragments (B-operand), pre-scaled, held in registers
        const bf16* Qb = Q + (size_t)(b * S_LEN + qt * 64 + wave * 16 + l) * DMODEL + h * HDIM;
        const bf16x8 qf0 = *(const bf16x8*)(Qb + quad * 8);
        const bf16x8 qf1 = *(const bf16x8*)(Qb + 32 + quad * 8);

        float m_run = NEG_INF, l_run = 0.0f;
        f32x4 acc[4] = {};

        for (int kt = 0; kt <= qt; ++kt) {
            __syncthreads();  // prior iter's LDS reads complete
            {   // stage K [key][d]
                const bf16* kg = K + (size_t)(b * S_LEN + kt * 64 + kr) * DMODEL + h * HDIM + ks;
                *(bf16x8*)&Ks[kr][ks]     = *(const bf16x8*)kg;
                *(bf16x8*)&Ks[kr][ks + 8] = *(const bf16x8*)(kg + 8);
            }
            {   // stage V transposed [d][key], packed pair writes
                const bf16* vg = V + (size_t)(b * S_LEN + kt * 64 + vk0) * DMODEL + h * HDIM + vds;
                bf16x8 v0 = *(const bf16x8*)vg;
                bf16x8 v1 = *(const bf16x8*)(vg + DMODEL);
#pragma unroll
                for (int i = 0; i < 8; ++i) {
                    U2 w; w.h[0] = v0[i]; w.h[1] = v1[i];
                    *(unsigned*)&Vt[vds + i][vk0] = w.u;
                }
            }
            if (wave == 0) {
                const int mv = amask[b * S_LEN + kt * 64 + lane];
                mk[lane] = mv ? 0.0f : NEG_INF;
                unsigned long long bal = __ballot(mv != 0);
                if (lane == 0) flagv = (bal == ~0ULL);
            }
            __syncthreads();
            const int allv = flagv;

            // S^T = K · Q^T : lane holds S^T[key = mi*16+quad*4+r][q = l]
            f32x4 sreg[4] = {};
#pragma unroll
            for (int mi = 0; mi < 4; ++mi) {
                bf16x8 kf0 = *(const bf16x8*)&Ks[mi * 16 + l][quad * 8];
                bf16x8 kf1 = *(const bf16x8*)&Ks[mi * 16 + l][32 + quad * 8];
                sreg[mi] = __builtin_amdgcn_mfma_f32_16x16x32_bf16(kf0, qf0, sreg[mi], 0, 0, 0);
                sreg[mi] = __builtin_amdgcn_mfma_f32_16x16x32_bf16(kf1, qf1, sreg[mi], 0, 0, 0);
            }
            if (!allv) {
#pragma unroll
                for (int mi = 0; mi < 4; ++mi) {
                    F4 m4; m4.v = *(const float4*)&mk[mi * 16 + quad * 4];
#pragma unroll
                    for (int r = 0; r < 4; ++r) sreg[mi][r] += m4.f[r];
                }
            }
            if (kt == qt) {   // diagonal tile: causal mask
#pragma unroll
                for (int mi = 0; mi < 4; ++mi)
#pragma unroll
                    for (int r = 0; r < 4; ++r)
                        if (mi * 16 + quad * 4 + r > wave * 16 + l)
                            sreg[mi][r] = NEG_INF;
            }

            // online softmax (per-lane: one query's 16 keys; 2 shfl levels for 64)
            float mloc = sreg[0][0];
#pragma unroll
            for (int mi = 0; mi < 4; ++mi)
#pragma unroll
                for (int r = 0; r < 4; ++r) mloc = fmaxf(mloc, sreg[mi][r]);
            mloc = fmaxf(mloc, __shfl_xor(mloc, 16, 64));
            mloc = fmaxf(mloc, __shfl_xor(mloc, 32, 64));
            const float mn = fmaxf(m_run, mloc);
            const float alpha = __builtin_amdgcn_exp2f(m_run - mn);
            m_run = mn;
            float ls = 0.0f;
#pragma unroll
            for (int mi = 0; mi < 4; ++mi)
#pragma unroll
                for (int r = 0; r < 4; ++r) {
                    const float p = __builtin_amdgcn_exp2f(sreg[mi][r] - mn);
                    sreg[mi][r] = p;
                    ls += p;
                }
            ls += __shfl_xor(ls, 16, 64);
            ls += __shfl_xor(ls, 32, 64);
            l_run = l_run * alpha + ls;
#pragma unroll
            for (int mi = 0; mi < 4; ++mi)
#pragma unroll
                for (int r = 0; r < 4; ++r) acc[mi][r] *= alpha;

            // pack P^T to bf16 dwords: pk[mi][t] = keys (mi*16+quad*4+2t, +1)
            unsigned pk[4][2];
#pragma unroll
            for (int mi = 0; mi < 4; ++mi) {
                U2 w0; w0.h[0] = (bf16)sreg[mi][0]; w0.h[1] = (bf16)sreg[mi][1];
                U2 w1; w1.h[0] = (bf16)sreg[mi][2]; w1.h[1] = (bf16)sreg[mi][3];
                pk[mi][0] = w0.u; pk[mi][1] = w1.u;
            }
            // assemble B-frags of P^T: lane(quad,l) needs keys kc*32+quad*8+j, q=l
            bf16x8 pfrag[2];
#pragma unroll
            for (int kc = 0; kc < 2; ++kc) {
                U8 u;
#pragma unroll
                for (int t = 0; t < 2; ++t) {
                    const unsigned a0 = (unsigned)__shfl((int)pk[2 * kc][t],     srcA, 64);
                    const unsigned b0 = (unsigned)__shfl((int)pk[2 * kc + 1][t], srcA, 64);
                    u.u[t] = qh ? b0 : a0;
                    const unsigned a1 = (unsigned)__shfl((int)pk[2 * kc][t],     srcB, 64);
                    const unsigned b1 = (unsigned)__shfl((int)pk[2 * kc + 1][t], srcB, 64);
                    u.u[2 + t] = qh ? b1 : a1;
                }
                pfrag[kc] = u.v;
            }
            // O^T += V^T · P^T : lane holds O^T[d = mi*16+quad*4+r][q = l]
#pragma unroll
            for (int mi = 0; mi < 4; ++mi) {
                bf16x8 vf0 = *(const bf16x8*)&Vt[mi * 16 + l][quad * 8];
                bf16x8 vf1 = *(const bf16x8*)&Vt[mi * 16 + l][32 + quad * 8];
                acc[mi] = __builtin_amdgcn_mfma_f32_16x16x32_bf16(vf0, pfrag[0], acc[mi], 0, 0, 0);
                acc[mi] = __builtin_amdgcn_mfma_f32_16x16x32_bf16(vf1, pfrag[1], acc[mi], 0, 0, 0);
            }
        }

        // epilogue: lane owns query q = wave*16+l, d = mi*16+quad*4+r
        const float rinv = 1.0f / l_run;
#pragma unroll
        for (int mi = 0; mi < 4; ++mi) {
            U2 w0; w0.h[0] = (bf16)(acc[mi][0] * rinv); w0.h[1] = (bf16)(acc[mi][1] * rinv);
            U2 w1; w1.h[0] = (bf16)(acc[mi][2] * rinv); w1.h[1] = (bf16)(acc[mi][3] * rinv);
            *(unsigned*)&Os[wave * 16 + l][mi * 16 + quad * 4]     = w0.u;
            *(unsigned*)&Os[wave * 16 + l][mi * 16 + quad * 4 + 2] = w1.u;
        }
        __syncthreads();
        {   // coalesced store
            const int orow = tid >> 2, oseg = (tid & 3) * 16;
            bf16* Og = O + (size_t)(b * S_LEN + qt * 64 + orow) * DMODEL + h * HDIM + oseg;
            *(bf16x8*)Og       = *(const bf16x8*)&Os[orow][oseg];
            *(bf16x8*)(Og + 8) = *(const bf16x8*)&Os[orow][oseg + 8];
        }
    }
}

// ---------------- launcher ----------------
extern "C" void kernel_launch(void* const* d_in, const int* in_sizes, int n_in,
                              void* d_out, int out_size, void* d_ws, size_t ws_size,
                              hipStream_t stream) {
    const float* x     = (const float*)d_in[0];
    const int*   amask = (const int*)  d_in[1];
    const float* ln1_g = (const float*)d_in[2];
    const float* ln1_b = (const float*)d_in[3];
    const float* ln2_g = (const float*)d_in[4];
    const float* ln2_b = (const float*)d_in[5];
    const float* Wq = (const float*)d_in[6];  const float* bq = (const float*)d_in[7];
    const float* Wk = (const float*)d_in[8];  const float* bk = (const float*)d_in[9];
    const float* Wv = (const float*)d_in[10]; const float* bv = (const float*)d_in[11];
    const float* Wo = (const float*)d_in[12]; const float* bo = (const float*)d_in[13];
    const float* W1 = (const float*)d_in[14]; const float* b1 = (const float*)d_in[15];
    const float* W2 = (const float*)d_in[16]; const float* b2 = (const float*)d_in[17];
    float* out = (float*)d_out;

    char* ws = (char*)d_ws;
    const size_t WSML = (size_t)DMODEL * DMODEL * 2;
    const size_t WBIG = (size_t)DMODEL * DFF_ * 2;
    bf16* Wqt = (bf16*)(ws + 0 * WSML);
    bf16* Wkt = (bf16*)(ws + 1 * WSML);
    bf16* Wvt = (bf16*)(ws + 2 * WSML);
    bf16* Wot = (bf16*)(ws + 3 * WSML);
    bf16* W1t = (bf16*)(ws + 4 * WSML);
    bf16* W2t = (bf16*)(ws + 4 * WSML + WBIG);
    char* act = ws + 4 * WSML + 2 * WBIG;

    const size_t HB = (size_t)MROWS * DMODEL * 2;   // bf16 activation
    const size_t FB = (size_t)MROWS * DMODEL * 4;   // fp32 activation
    bf16*  h    = (bf16*)(act);            // LN1 out; later ctx; later h2
    bf16*  qb   = (bf16*)(act + HB);
    bf16*  kb   = (bf16*)(act + 2 * HB);
    bf16*  vb   = (bf16*)(act + 3 * HB);
    bf16*  ctx  = h;
    float* x1   = (float*)(act + 4 * HB);
    bf16*  f    = (bf16*)(act + 4 * HB + FB);
    bf16*  h2   = h;

    const float SCL = 0.125f * 1.44269504089f;  // 1/sqrt(64) * log2(e), folded into Q

    // 0. weight transpose+convert
    wtrans_kernel<<<dim3(DMODEL / 64, DMODEL / 64), 256, 0, stream>>>(Wq, Wqt, DMODEL, DMODEL);
    wtrans_kernel<<<dim3(DMODEL / 64, DMODEL / 64), 256, 0, stream>>>(Wk, Wkt, DMODEL, DMODEL);
    wtrans_kernel<<<dim3(DMODEL / 64, DMODEL / 64), 256, 0, stream>>>(Wv, Wvt, DMODEL, DMODEL);
    wtrans_kernel<<<dim3(DMODEL / 64, DMODEL / 64), 256, 0, stream>>>(Wo, Wot, DMODEL, DMODEL);
    wtrans_kernel<<<dim3(DFF_ / 64, DMODEL / 64), 256, 0, stream>>>(W1, W1t, DMODEL, DFF_);
    wtrans_kernel<<<dim3(DMODEL / 64, DFF_ / 64), 256, 0, stream>>>(W2, W2t, DFF_, DMODEL);

    // 1. LN1 -> h (bf16)
    ln_kernel<bf16><<<MROWS, 256, 0, stream>>>(x, ln1_g, ln1_b, h);
    // 2. QKV fused, bf16 out; Q pre-scaled by SCL
    mgemm_kernel<false, false, true><<<dim3(DMODEL / 128, MROWS / 128, 3), 256, 0, stream>>>(
        h, Wqt, bq, qb, Wkt, bk, kb, Wvt, bv, vb, nullptr, MROWS, DMODEL, DMODEL,
        SCL, 1.0f, 1.0f);
    // 3. transposed-S MFMA flash attention -> ctx (bf16)
    mattn_kernel<<<dim3(32, NHEAD, 2), 256, 0, stream>>>(qb, kb, vb, amask, ctx);
    // 4. out proj + residual(x) -> x1 (fp32)
    mgemm_kernel<false, true, false><<<dim3(DMODEL / 128, MROWS / 128, 1), 256, 0, stream>>>(
        ctx, Wot, bo, x1, Wot, bo, x1, Wot, bo, x1, x, MROWS, DMODEL, DMODEL,
        1.0f, 1.0f, 1.0f);
    // 5. LN2 -> h2 (bf16)
    ln_kernel<bf16><<<MROWS, 256, 0, stream>>>(x1, ln2_g, ln2_b, h2);
    // 6. FF1 + relu -> f (bf16)
    mgemm_kernel<true, false, true><<<dim3(DFF_ / 128, MROWS / 128, 1), 256, 0, stream>>>(
        h2, W1t, b1, f, W1t, b1, f, W1t, b1, f, nullptr, MROWS, DFF_, DMODEL,
        1.0f, 1.0f, 1.0f);
    // 7. FF2 + residual(x1) -> out (fp32)
    mgemm_kernel<false, true, false><<<dim3(DMODEL / 128, MROWS / 128, 1), 256, 0, stream>>>(
        f, W2t, b2, out, W2t, b2, out, W2t, b2, out, x1, MROWS, DMODEL, DFF_,
        1.0f, 1.0f, 1.0f);
}